// Round 6
// baseline (824.109 us; speedup 1.0000x reference)
//
#include <hip/hip_runtime.h>

// HyperConv: y[b,o,t] = sum_{i<3} sum_{c<16} x[b,c,t+8-4i] * w_b[i*16+c][o]
// w_b = LeakyReLU(p[b]@W1 + b1) @ W2 + b2, reshaped [48][16].
//
// R6: outstanding-bytes theory. R0/R2/R3/R5 all offered the memory system
// ~20-35 KB in-flight per CU and all landed at 1.9-2.4 TB/s; the 6.3 TB/s
// copy bench offers >100 KB/CU. BW = inflight/latency (loaded latency
// ~2-4us) fits every data point. Single-lever change from R2: prefetch
// distance 3 -> 7 (NBUF 8, LDS 36 KB -> 4 blocks/CU, 16 waves/CU), row
// loop fully unrolled so counted-vmcnt immediates are compile-time.
// Everything else identical to R2 (2048 blocks, tile map, nt stores).

#define NB 32
#define IN_CH 16
#define OUT_CH 16
#define KW 3
#define COND 8
#define T_OUT 65536
#define PADT 8
#define XT (T_OUT + PADT)            // 65544 floats, row stride of x
#define W2COLS (IN_CH * OUT_CH * KW) // 768
#define TPB 256
#define TPT 4                        // t-positions per thread
#define T_PER_BLOCK (TPB * TPT)      // 1024
#define BLOCKS_PER_B (T_OUT / T_PER_BLOCK) // 64
#define ROWF (T_PER_BLOCK + PADT)    // 1032 floats staged per channel row
#define NBUF 8                       // rolling buffers, distance-7 prefetch
#define PFD 7                        // prefetch distance

typedef const __attribute__((address_space(1))) void* gvp;
typedef __attribute__((address_space(3))) void* svp;
typedef float f32x4 __attribute__((ext_vector_type(4)));

// vmcnt(N)-only wait with a guaranteed compile-time immediate.
// gfx9 encoding: vmcnt[3:0]=imm[3:0], vmcnt[5:4]=imm[15:14],
// expcnt=imm[6:4] (7=no wait), lgkmcnt=imm[11:8] (15=no wait).
template <int N>
__device__ __forceinline__ void wait_vmcnt() {
    static_assert(N >= 0 && N < 64, "vmcnt range");
    __builtin_amdgcn_s_waitcnt(0x0F70 | (N & 15) | ((N >> 4) << 14));
}

// Stage one 1032-float row into LDS: wave w covers bytes [w*1024,(w+1)*1024)
// (linear dest = base+lane*16 per global_load_lds semantics); wave 0 lanes
// 0..1 add the 8-float halo. => 1 vmem op/row/wave (2 for wave 0).
__device__ __forceinline__ void stage_row(const float* __restrict__ g,
                                          float* l, int wid, int lane)
{
    __builtin_amdgcn_global_load_lds((gvp)(g + wid * 256 + lane * 4),
                                     (svp)(l + wid * 256), 16, 0, 0);
    if (wid == 0 && lane < 2)
        __builtin_amdgcn_global_load_lds((gvp)(g + T_PER_BLOCK + lane * 4),
                                         (svp)(l + T_PER_BLOCK), 16, 0, 0);
}

// One channel-row: 3 taps x 16 outputs x 4 t = 192 FMA/thread.
__device__ __forceinline__ void compute_row(const float* __restrict__ xrow,
                                            const float* __restrict__ w_lds,
                                            int c, float4* acc, int tid)
{
    const float4 l0 = *(const float4*)(xrow + tid * 4);      // tap i=2 (+0)
    const float4 l1 = *(const float4*)(xrow + tid * 4 + 4);  // tap i=1 (+4)
    const float4 l2 = *(const float4*)(xrow + tid * 4 + 8);  // tap i=0 (+8)
    const float4 vs[KW] = {l2, l1, l0};                      // vs[i]: offset 8-4i
#pragma unroll
    for (int i = 0; i < KW; ++i) {
        const float4 v = vs[i];
        const float* wrow = w_lds + (i * IN_CH + c) * OUT_CH;
#pragma unroll
        for (int og = 0; og < 4; ++og) {
            const float4 wv = *(const float4*)(wrow + og * 4);
            float4* a = acc + og * 4;
            a[0].x += v.x * wv.x; a[0].y += v.y * wv.x;
            a[0].z += v.z * wv.x; a[0].w += v.w * wv.x;
            a[1].x += v.x * wv.y; a[1].y += v.y * wv.y;
            a[1].z += v.z * wv.y; a[1].w += v.w * wv.y;
            a[2].x += v.x * wv.z; a[2].y += v.y * wv.z;
            a[2].z += v.z * wv.z; a[2].w += v.w * wv.z;
            a[3].x += v.x * wv.w; a[3].y += v.y * wv.w;
            a[3].z += v.z * wv.w; a[3].w += v.w * wv.w;
        }
    }
}

__global__ __launch_bounds__(TPB)
void hyperconv_kernel(const float* __restrict__ x,
                      const float* __restrict__ p,
                      const float* __restrict__ W1,
                      const float* __restrict__ b1,
                      const float* __restrict__ W2,
                      const float* __restrict__ b2,
                      float* __restrict__ y)
{
    __shared__ __align__(16) float xbuf[NBUF][ROWF];  // 33 KiB
    __shared__ float h_lds[IN_CH];
    __shared__ __align__(16) float w_lds[W2COLS];     // 3 KiB

    const int tid    = threadIdx.x;
    const int wid    = tid >> 6;
    const int lane   = tid & 63;
    const int b      = blockIdx.x / BLOCKS_PER_B;
    const int tchunk = blockIdx.x % BLOCKS_PER_B;
    const int t0b    = tchunk * T_PER_BLOCK;

    const float* xrb = x + (size_t)b * IN_CH * XT + t0b;

    // Prologue: rows 0..6 in flight under the hypernet phase.
#pragma unroll
    for (int r = 0; r < PFD; ++r)
        stage_row(xrb + r * XT, xbuf[r], wid, lane);

    // ---- hypernetwork: h = LeakyReLU(p[b] @ W1 + b1) ----
    if (tid < IN_CH) {
        float acc = b1[tid];
#pragma unroll
        for (int j = 0; j < COND; ++j)
            acc += p[b * COND + j] * W1[j * IN_CH + tid];
        h_lds[tid] = acc > 0.f ? acc : 0.2f * acc;
    }
    __syncthreads();

    // ---- w = h @ W2 + b2 : 768 entries, 3 per thread ----
#pragma unroll
    for (int r = 0; r < 3; ++r) {
        const int n = tid * 3 + r;
        float acc = b2[n];
#pragma unroll
        for (int c = 0; c < IN_CH; ++c)
            acc += h_lds[c] * W2[c * W2COLS + n];
        w_lds[n] = acc;
    }
    __syncthreads();   // drains vmcnt(0): rows 0..6 resident, clean baseline

    float4 acc[OUT_CH];
#pragma unroll
    for (int o = 0; o < OUT_CH; ++o) acc[o] = make_float4(0.f, 0.f, 0.f, 0.f);

    // ---- main pipeline, fully unrolled: compute row r, rows r+1..r+7 in
    // flight. Post-sync bookkeeping (per wave, in-order vmem queue): iters
    // 0..r stage rows 7..r+7, so ops younger than row r's load (issued at
    // iter r-7; prologue rows 0..6 drained by the sync) number
    // min(r+7,15)-r -> wait vmcnt(7) while staging, vmcnt(15-r) in the tail.
    // Wave 0 issues 2 ops/row (halo) -> double the immediates.
    // Buffer safety: stage(r+7) overwrites buf (r-1)&7, whose readers all
    // passed iteration r-1's trailing barrier.
#pragma unroll
    for (int r = 0; r < IN_CH; ++r) {
        __builtin_amdgcn_sched_barrier(0);
        if (r + PFD < IN_CH)
            stage_row(xrb + (r + PFD) * XT, xbuf[(r + PFD) & (NBUF - 1)], wid, lane);
        constexpr int младшие = 0; (void)младшие;
        {
            constexpr int rem[IN_CH] = {7,7,7,7,7,7,7,7,7, 6,5,4,3,2,1,0};
            // r is a compile-time constant under full unroll:
            switch (r) {
#define WAITCASE(R) case R: if (wid == 0) wait_vmcnt<2*rem[R]>(); \
                            else          wait_vmcnt<rem[R]>(); break;
                WAITCASE(0)  WAITCASE(1)  WAITCASE(2)  WAITCASE(3)
                WAITCASE(4)  WAITCASE(5)  WAITCASE(6)  WAITCASE(7)
                WAITCASE(8)  WAITCASE(9)  WAITCASE(10) WAITCASE(11)
                WAITCASE(12) WAITCASE(13) WAITCASE(14) WAITCASE(15)
#undef WAITCASE
            }
        }
        __builtin_amdgcn_s_barrier();            // row r landed for all waves
        __builtin_amdgcn_sched_barrier(0);
        compute_row(xbuf[r & (NBUF - 1)], w_lds, r, acc, tid);
        __builtin_amdgcn_sched_barrier(0);
        if (r + PFD < IN_CH)
            __builtin_amdgcn_s_barrier();        // readers done before overwrite
    }

    // ---- store: nontemporal so 131 MB of y doesn't evict x from L3 ----
    float* yb = y + (size_t)b * OUT_CH * T_OUT + t0b + tid * TPT;
#pragma unroll
    for (int o = 0; o < OUT_CH; ++o) {
        const float4 a = acc[o];
        f32x4 v = {a.x, a.y, a.z, a.w};
        __builtin_nontemporal_store(v, (f32x4*)(yb + o * T_OUT));
    }
}

extern "C" void kernel_launch(void* const* d_in, const int* in_sizes, int n_in,
                              void* d_out, int out_size, void* d_ws, size_t ws_size,
                              hipStream_t stream) {
    const float* x  = (const float*)d_in[0];
    const float* p  = (const float*)d_in[1];
    const float* W1 = (const float*)d_in[2];
    const float* b1 = (const float*)d_in[3];
    const float* W2 = (const float*)d_in[4];
    const float* b2 = (const float*)d_in[5];
    float* y = (float*)d_out;

    dim3 grid(NB * BLOCKS_PER_B);   // 2048 blocks, 4/CU resident (36 KB LDS)
    dim3 block(TPB);
    hyperconv_kernel<<<grid, block, 0, stream>>>(x, p, W1, b1, W2, b2, y);
}

// Round 7
// 255.818 us; speedup vs baseline: 3.2215x; 3.2215x over previous
//
#include <hip/hip_runtime.h>

// HyperConv: y[b,o,t] = sum_{i<3} sum_{c<16} x[b,c,t+8-4i] * w_b[i*16+c][o]
// w_b = LeakyReLU(p[b]@W1 + b1) @ W2 + b2, reshaped [48][16].
//
// R7: outstanding-bytes theory, clean re-run. R6's spill accident proved
// the memory system sustains 3.3 TB/s on this footprint when enough bytes
// are in flight; all clean kernels offered only ~20-35 KB/CU and sat at
// 2.3 TB/s. This is R2's EXACT proven structure (rolled loop, runtime r,
// inline-asm fixed-immediate waits, 56 VGPR codegen) with one lever moved:
// prefetch distance 3 -> 7 (NBUF 8, steady wait vmcnt(7)/wave0 vmcnt(14),
// tail peels 7 rows after one vmcnt(0)). Spill sentinels: VGPR<=72,
// FETCH~68MB, WRITE~131MB — if violated, round is void.

#define NB 32
#define IN_CH 16
#define OUT_CH 16
#define KW 3
#define COND 8
#define T_OUT 65536
#define PADT 8
#define XT (T_OUT + PADT)            // 65544 floats, row stride of x
#define W2COLS (IN_CH * OUT_CH * KW) // 768
#define TPB 256
#define TPT 4                        // t-positions per thread
#define T_PER_BLOCK (TPB * TPT)      // 1024
#define BLOCKS_PER_B (T_OUT / T_PER_BLOCK) // 64
#define ROWF (T_PER_BLOCK + PADT)    // 1032 floats staged per channel row
#define NBUF 8                       // rolling buffers
#define PFD 7                        // prefetch distance

typedef const __attribute__((address_space(1))) void* gvp;
typedef __attribute__((address_space(3))) void* svp;
typedef float f32x4 __attribute__((ext_vector_type(4)));

// Stage one 1032-float row into LDS: wave w covers bytes [w*1024,(w+1)*1024)
// (linear dest = base+lane*16 per global_load_lds semantics); wave 0 lanes
// 0..1 add the 8-float halo. => 1 vmem op/row/wave (2 for wave 0).
__device__ __forceinline__ void stage_row(const float* __restrict__ g,
                                          float* l, int wid, int lane)
{
    __builtin_amdgcn_global_load_lds((gvp)(g + wid * 256 + lane * 4),
                                     (svp)(l + wid * 256), 16, 0, 0);
    if (wid == 0 && lane < 2)
        __builtin_amdgcn_global_load_lds((gvp)(g + T_PER_BLOCK + lane * 4),
                                         (svp)(l + T_PER_BLOCK), 16, 0, 0);
}

// One channel-row: 3 taps x 16 outputs x 4 t = 192 FMA/thread.
__device__ __forceinline__ void compute_row(const float* __restrict__ xrow,
                                            const float* __restrict__ w_lds,
                                            int c, float4* acc, int tid)
{
    const float4 l0 = *(const float4*)(xrow + tid * 4);      // tap i=2 (+0)
    const float4 l1 = *(const float4*)(xrow + tid * 4 + 4);  // tap i=1 (+4)
    const float4 l2 = *(const float4*)(xrow + tid * 4 + 8);  // tap i=0 (+8)
    const float4 vs[KW] = {l2, l1, l0};                      // vs[i]: offset 8-4i
#pragma unroll
    for (int i = 0; i < KW; ++i) {
        const float4 v = vs[i];
        const float* wrow = w_lds + (i * IN_CH + c) * OUT_CH;
#pragma unroll
        for (int og = 0; og < 4; ++og) {
            const float4 wv = *(const float4*)(wrow + og * 4);
            float4* a = acc + og * 4;
            a[0].x += v.x * wv.x; a[0].y += v.y * wv.x;
            a[0].z += v.z * wv.x; a[0].w += v.w * wv.x;
            a[1].x += v.x * wv.y; a[1].y += v.y * wv.y;
            a[1].z += v.z * wv.y; a[1].w += v.w * wv.y;
            a[2].x += v.x * wv.z; a[2].y += v.y * wv.z;
            a[2].z += v.z * wv.z; a[2].w += v.w * wv.z;
            a[3].x += v.x * wv.w; a[3].y += v.y * wv.w;
            a[3].z += v.z * wv.w; a[3].w += v.w * wv.w;
        }
    }
}

__global__ __launch_bounds__(TPB)
void hyperconv_kernel(const float* __restrict__ x,
                      const float* __restrict__ p,
                      const float* __restrict__ W1,
                      const float* __restrict__ b1,
                      const float* __restrict__ W2,
                      const float* __restrict__ b2,
                      float* __restrict__ y)
{
    __shared__ __align__(16) float xbuf[NBUF][ROWF];  // 33 KiB
    __shared__ float h_lds[IN_CH];
    __shared__ __align__(16) float w_lds[W2COLS];     // 3 KiB

    const int tid    = threadIdx.x;
    const int wid    = tid >> 6;
    const int lane   = tid & 63;
    const int b      = blockIdx.x / BLOCKS_PER_B;
    const int tchunk = blockIdx.x % BLOCKS_PER_B;
    const int t0b    = tchunk * T_PER_BLOCK;

    const float* xrb = x + (size_t)b * IN_CH * XT + t0b;

    // Prologue: rows 0..6 in flight under the hypernet phase.
    stage_row(xrb + 0 * XT, xbuf[0], wid, lane);
    stage_row(xrb + 1 * XT, xbuf[1], wid, lane);
    stage_row(xrb + 2 * XT, xbuf[2], wid, lane);
    stage_row(xrb + 3 * XT, xbuf[3], wid, lane);
    stage_row(xrb + 4 * XT, xbuf[4], wid, lane);
    stage_row(xrb + 5 * XT, xbuf[5], wid, lane);
    stage_row(xrb + 6 * XT, xbuf[6], wid, lane);

    // ---- hypernetwork: h = LeakyReLU(p[b] @ W1 + b1) ----
    if (tid < IN_CH) {
        float acc = b1[tid];
#pragma unroll
        for (int j = 0; j < COND; ++j)
            acc += p[b * COND + j] * W1[j * IN_CH + tid];
        h_lds[tid] = acc > 0.f ? acc : 0.2f * acc;
    }
    __syncthreads();

    // ---- w = h @ W2 + b2 : 768 entries, 3 per thread ----
#pragma unroll
    for (int r = 0; r < 3; ++r) {
        const int n = tid * 3 + r;
        float acc = b2[n];
#pragma unroll
        for (int c = 0; c < IN_CH; ++c)
            acc += h_lds[c] * W2[c * W2COLS + n];
        w_lds[n] = acc;
    }
    __syncthreads();   // drains vmcnt(0): rows 0..6 resident, clean baseline

    float4 acc[OUT_CH];
#pragma unroll
    for (int o = 0; o < OUT_CH; ++o) acc[o] = make_float4(0.f, 0.f, 0.f, 0.f);

    // ---- main pipeline: compute row r while rows r+1..r+7 are in flight ----
    // vmcnt bookkeeping (per wave, in-order): before stage, queue holds rows
    // r..r+6 (7 ops; wave 0: 14 with halo). After stage(r+7): 8 ops. Wait for
    // row r => allow 7 youngest => vmcnt(7) (wave 0: vmcnt(14)).
    // Buffer safety: stage(r+7) overwrites buf (r-1)&7, whose readers all
    // passed iteration r-1's trailing barrier.
#pragma unroll 1
    for (int r = 0; r < 9; ++r) {
        __builtin_amdgcn_sched_barrier(0);
        stage_row(xrb + (r + PFD) * XT, xbuf[(r + PFD) & (NBUF - 1)], wid, lane);
        if (wid == 0) asm volatile("s_waitcnt vmcnt(14)" ::: "memory");
        else          asm volatile("s_waitcnt vmcnt(7)" ::: "memory");
        __builtin_amdgcn_s_barrier();            // row r landed for all waves
        __builtin_amdgcn_sched_barrier(0);
        compute_row(xbuf[r & (NBUF - 1)], w_lds, r, acc, tid);
        __builtin_amdgcn_sched_barrier(0);
        __builtin_amdgcn_s_barrier();            // readers done before overwrite
    }
    // ---- tail: rows 9..15 already issued (distinct buffers 1..7, no more
    // LDS writes), drain once, compute the remaining 7 rows ----
    asm volatile("s_waitcnt vmcnt(0)" ::: "memory");
    __builtin_amdgcn_s_barrier();
    __builtin_amdgcn_sched_barrier(0);
    compute_row(xbuf[ 9 & (NBUF - 1)], w_lds,  9, acc, tid);
    compute_row(xbuf[10 & (NBUF - 1)], w_lds, 10, acc, tid);
    compute_row(xbuf[11 & (NBUF - 1)], w_lds, 11, acc, tid);
    compute_row(xbuf[12 & (NBUF - 1)], w_lds, 12, acc, tid);
    compute_row(xbuf[13 & (NBUF - 1)], w_lds, 13, acc, tid);
    compute_row(xbuf[14 & (NBUF - 1)], w_lds, 14, acc, tid);
    compute_row(xbuf[15 & (NBUF - 1)], w_lds, 15, acc, tid);

    // ---- store: nontemporal so 131 MB of y doesn't evict x from L3 ----
    float* yb = y + (size_t)b * OUT_CH * T_OUT + t0b + tid * TPT;
#pragma unroll
    for (int o = 0; o < OUT_CH; ++o) {
        const float4 a = acc[o];
        f32x4 v = {a.x, a.y, a.z, a.w};
        __builtin_nontemporal_store(v, (f32x4*)(yb + o * T_OUT));
    }
}

extern "C" void kernel_launch(void* const* d_in, const int* in_sizes, int n_in,
                              void* d_out, int out_size, void* d_ws, size_t ws_size,
                              hipStream_t stream) {
    const float* x  = (const float*)d_in[0];
    const float* p  = (const float*)d_in[1];
    const float* W1 = (const float*)d_in[2];
    const float* b1 = (const float*)d_in[3];
    const float* W2 = (const float*)d_in[4];
    const float* b2 = (const float*)d_in[5];
    float* y = (float*)d_out;

    dim3 grid(NB * BLOCKS_PER_B);   // 2048 blocks
    dim3 block(TPB);
    hyperconv_kernel<<<grid, block, 0, stream>>>(x, p, W1, b1, W2, b2, y);
}

// Round 8
// 243.180 us; speedup vs baseline: 3.3889x; 1.0520x over previous
//
#include <hip/hip_runtime.h>

// HyperConv: y[b,o,t] = sum_{i<3} sum_{c<16} x[b,c,t+8-4i] * w_b[i*16+c][o]
// w_b = LeakyReLU(p[b]@W1 + b1) @ W2 + b2, reshaped [48][16].
//
// R8: deep-queue / zero-barrier regime. R6's spill accident (3.32 TB/s)
// ran ~64-deep per-wave unsynchronized vmem queues; all clean kernels had
// <=8-deep queues + barrier lockstep and sat at 2.2-2.4 TB/s. This version
// reproduces the deep regime with useful traffic only: rows are WAVE-
// PRIVATE (own 256-t span + own halo -> no cross-wave deps -> no barriers
// anywhere in the main loop). All 16 rows staged up front = 32 LDS-DMA ops
// (~17 KB) in flight per wave, 8 waves/CU => ~135 KB/CU offered (copy-bench
// territory). Compute drains via descending per-wave vmcnt ladder.
// Spill sentinels: VGPR<=96, FETCH~68MB, WRITE~131MB — else round void.

#define NB 32
#define IN_CH 16
#define OUT_CH 16
#define KW 3
#define COND 8
#define T_OUT 65536
#define PADT 8
#define XT (T_OUT + PADT)            // 65544 floats, row stride of x
#define W2COLS (IN_CH * OUT_CH * KW) // 768
#define TPB 256
#define TPT 4                        // t-positions per thread
#define T_PER_BLOCK (TPB * TPT)      // 1024
#define T_PER_WAVE 256               // wave-private t-span
#define BLOCKS_PER_B (T_OUT / T_PER_BLOCK) // 64
#define WROW (T_PER_WAVE + PADT)     // 264 floats per wave-private row

typedef const __attribute__((address_space(1))) void* gvp;
typedef __attribute__((address_space(3))) void* svp;
typedef float f32x4 __attribute__((ext_vector_type(4)));

// Stage one wave-private 264-float row: main op = 64 lanes x 16 B (1 KB),
// halo op = lanes 0..1 x 16 B (32 B at +1024 B). Lanes 0,1 exist in every
// wave so both ops always issue: exactly 2 vmcnt ops/row/wave.
__device__ __forceinline__ void stage_wrow(const float* __restrict__ g,
                                           float* l, int lane)
{
    __builtin_amdgcn_global_load_lds((gvp)(g + lane * 4), (svp)l, 16, 0, 0);
    if (lane < 2)
        __builtin_amdgcn_global_load_lds((gvp)(g + T_PER_WAVE + lane * 4),
                                         (svp)(l + T_PER_WAVE), 16, 0, 0);
}

// One channel-row: 3 taps x 16 outputs x 4 t = 192 FMA/thread.
// xrow is the wave's private row; lane l reads floats [4l, 4l+11].
__device__ __forceinline__ void compute_row(const float* __restrict__ xrow,
                                            const float* __restrict__ w_lds,
                                            int c, float4* acc, int lane)
{
    const float4 l0 = *(const float4*)(xrow + lane * 4);      // tap i=2 (+0)
    const float4 l1 = *(const float4*)(xrow + lane * 4 + 4);  // tap i=1 (+4)
    const float4 l2 = *(const float4*)(xrow + lane * 4 + 8);  // tap i=0 (+8)
    const float4 vs[KW] = {l2, l1, l0};                       // vs[i]: offset 8-4i
#pragma unroll
    for (int i = 0; i < KW; ++i) {
        const float4 v = vs[i];
        const float* wrow = w_lds + (i * IN_CH + c) * OUT_CH;
#pragma unroll
        for (int og = 0; og < 4; ++og) {
            const float4 wv = *(const float4*)(wrow + og * 4);
            float4* a = acc + og * 4;
            a[0].x += v.x * wv.x; a[0].y += v.y * wv.x;
            a[0].z += v.z * wv.x; a[0].w += v.w * wv.x;
            a[1].x += v.x * wv.y; a[1].y += v.y * wv.y;
            a[1].z += v.z * wv.y; a[1].w += v.w * wv.y;
            a[2].x += v.x * wv.z; a[2].y += v.y * wv.z;
            a[2].z += v.z * wv.z; a[2].w += v.w * wv.z;
            a[3].x += v.x * wv.w; a[3].y += v.y * wv.w;
            a[3].z += v.z * wv.w; a[3].w += v.w * wv.w;
        }
    }
}

__global__ __launch_bounds__(TPB)
void hyperconv_kernel(const float* __restrict__ x,
                      const float* __restrict__ p,
                      const float* __restrict__ W1,
                      const float* __restrict__ b1,
                      const float* __restrict__ W2,
                      const float* __restrict__ b2,
                      float* __restrict__ y)
{
    __shared__ __align__(16) float xr[4][IN_CH][WROW]; // 66 KiB, wave-private rows
    __shared__ float h_lds[IN_CH];
    __shared__ __align__(16) float w_lds[W2COLS];      // 3 KiB

    const int tid    = threadIdx.x;
    const int wid    = tid >> 6;
    const int lane   = tid & 63;
    const int b      = blockIdx.x / BLOCKS_PER_B;
    const int tchunk = blockIdx.x % BLOCKS_PER_B;
    const int t0b    = tchunk * T_PER_BLOCK;

    // ---- hypernetwork FIRST (its global loads + full drain leave a clean
    //      vmem queue for the stage burst) ----
    if (tid < IN_CH) {
        float acc = b1[tid];
#pragma unroll
        for (int j = 0; j < COND; ++j)
            acc += p[b * COND + j] * W1[j * IN_CH + tid];
        h_lds[tid] = acc > 0.f ? acc : 0.2f * acc;
    }
    __syncthreads();

    // ---- w = h @ W2 + b2 : 768 entries, 3 per thread ----
#pragma unroll
    for (int r = 0; r < 3; ++r) {
        const int n = tid * 3 + r;
        float acc = b2[n];
#pragma unroll
        for (int c = 0; c < IN_CH; ++c)
            acc += h_lds[c] * W2[c * W2COLS + n];
        w_lds[n] = acc;
    }
    __syncthreads();   // drains vmcnt(0)+lgkmcnt(0): w_lds visible, queue clean

    // ---- stage burst: ALL 16 wave-private rows, 32 ops, ~17 KB in flight ----
    const float* xwb = x + (size_t)b * IN_CH * XT + t0b + wid * T_PER_WAVE;
#pragma unroll
    for (int c = 0; c < IN_CH; ++c)
        stage_wrow(xwb + c * XT, &xr[wid][c][0], lane);
    __builtin_amdgcn_sched_barrier(0);

    float4 acc[OUT_CH];
#pragma unroll
    for (int o = 0; o < OUT_CH; ++o) acc[o] = make_float4(0.f, 0.f, 0.f, 0.f);

    // ---- drain ladder: row r ready when its 2 ops (positions 2r,2r+1 in the
    // wave's in-order queue) complete => allow 32-2(r+1) = 30-2r younger ops.
    // No barriers: rows are wave-private; ds_read ordering vs DMA is enforced
    // by the asm memory clobber + program order.
#define STEP(R, V) \
    asm volatile("s_waitcnt vmcnt(" #V ")" ::: "memory"); \
    compute_row(&xr[wid][R][0], w_lds, R, acc, lane);
    STEP(0, 30)  STEP(1, 28)  STEP(2, 26)  STEP(3, 24)
    STEP(4, 22)  STEP(5, 20)  STEP(6, 18)  STEP(7, 16)
    STEP(8, 14)  STEP(9, 12)  STEP(10, 10) STEP(11, 8)
    STEP(12, 6)  STEP(13, 4)  STEP(14, 2)  STEP(15, 0)
#undef STEP

    // ---- store: nontemporal, 16 streams x 16 B per thread ----
    float* yb = y + (size_t)b * OUT_CH * T_OUT + t0b + wid * T_PER_WAVE + lane * TPT;
#pragma unroll
    for (int o = 0; o < OUT_CH; ++o) {
        const float4 a = acc[o];
        f32x4 v = {a.x, a.y, a.z, a.w};
        __builtin_nontemporal_store(v, (f32x4*)(yb + o * T_OUT));
    }
}

extern "C" void kernel_launch(void* const* d_in, const int* in_sizes, int n_in,
                              void* d_out, int out_size, void* d_ws, size_t ws_size,
                              hipStream_t stream) {
    const float* x  = (const float*)d_in[0];
    const float* p  = (const float*)d_in[1];
    const float* W1 = (const float*)d_in[2];
    const float* b1 = (const float*)d_in[3];
    const float* W2 = (const float*)d_in[4];
    const float* b2 = (const float*)d_in[5];
    float* y = (float*)d_out;

    dim3 grid(NB * BLOCKS_PER_B);   // 2048 blocks, 2/CU (70.7 KB LDS)
    dim3 block(TPB);
    hyperconv_kernel<<<grid, block, 0, stream>>>(x, p, W1, b1, W2, b2, y);
}